// Round 8
// baseline (511.345 us; speedup 1.0000x reference)
//
#include <hip/hip_runtime.h>
#include <hip/hip_bf16.h>

typedef __bf16 bf16_t;
typedef __attribute__((ext_vector_type(8))) __bf16 bf16x8;
typedef __attribute__((ext_vector_type(4))) float f32x4;
typedef __attribute__((ext_vector_type(8))) float f32x8;

// ---------------- degree ----------------
__global__ void k_deg_count(const int* __restrict__ dst, int* __restrict__ deg, int E) {
    int e = blockIdx.x * blockDim.x + threadIdx.x;
    if (e < E) atomicAdd(&deg[dst[e]], 1);
}

// ---------------- dinv + scan phase 1 (fused) -----------------------------
__global__ __launch_bounds__(256) void k_dinv_scan1(const int* __restrict__ deg,
                                                    float* __restrict__ dinv,
                                                    int* __restrict__ bsum, int n) {
    __shared__ int red[256];
    int b = blockIdx.x, t = threadIdx.x;
    int base = b * 1024 + t * 4;
    int s = 0;
#pragma unroll
    for (int j = 0; j < 4; ++j) {
        int i = base + j;
        if (i < n) { int d = deg[i]; s += d; dinv[i] = rsqrtf((float)(d + 1)); }
    }
    red[t] = s;
    __syncthreads();
    for (int d = 128; d > 0; d >>= 1) {
        if (t < d) red[t] += red[t + d];
        __syncthreads();
    }
    if (t == 0) bsum[b] = red[0];
}

// phase 2: single block scans <=256 block sums (exclusive), writes rowPtr[n]=E
__global__ __launch_bounds__(256) void k_scan2(int* __restrict__ bsum, int nb,
                                               int* __restrict__ rowPtr, int n) {
    __shared__ int s[256];
    int t = threadIdx.x;
    int v = (t < nb) ? bsum[t] : 0;
    s[t] = v;
    __syncthreads();
    for (int d = 1; d < 256; d <<= 1) {   // Hillis-Steele inclusive
        int u = (t >= d) ? s[t - d] : 0;
        __syncthreads();
        s[t] += u;
        __syncthreads();
    }
    if (t < nb) bsum[t] = s[t] - v;       // exclusive block offset
    if (t == 255) rowPtr[n] = s[255];     // total = E
}

// ------- pack B[K,N] f32 -> bf16 MFMA fragments ---------------------------
__device__ inline void packB_one(const float* __restrict__ B, bf16_t* __restrict__ Bp,
                                 int N, int idx) {
    int j    = idx & 7;
    int lane = (idx >> 3) & 63;
    int st   = idx >> 9;
    int nt   = N >> 4;
    int s = st / nt, t = st - s * nt;
    int k = s * 32 + (lane >> 4) * 8 + j;
    int n = t * 16 + (lane & 15);
    Bp[idx] = (bf16_t)B[(size_t)k * N + n];
}

// phase 3: block-local exclusive scan + block offset -> rowPtr; also packs W1
__global__ __launch_bounds__(256) void k_scan3(const int* __restrict__ deg,
                                               const int* __restrict__ bsum,
                                               int* __restrict__ rowPtr, int n,
                                               const float* __restrict__ W1,
                                               bf16_t* __restrict__ Bp1) {
    __shared__ int red[256];
    int b = blockIdx.x, t = threadIdx.x;
    int base = b * 1024 + t * 4;
    int v[4]; int s = 0;
#pragma unroll
    for (int j = 0; j < 4; ++j) { int i = base + j; v[j] = (i < n) ? deg[i] : 0; s += v[j]; }
    red[t] = s;
    __syncthreads();
    for (int d = 1; d < 256; d <<= 1) {
        int u = (t >= d) ? red[t - d] : 0;
        __syncthreads();
        red[t] += u;
        __syncthreads();
    }
    int run = bsum[b] + red[t] - s;
#pragma unroll
    for (int j = 0; j < 4; ++j) { int i = base + j; if (i < n) rowPtr[i] = run; run += v[j]; }
    // ---- independent: pack W1 (256x128 f32 -> 32768 bf16 fragments) ----
    int tid = b * 256 + t;                 // 0..25087
    const int T1 = (256 / 32) * (128 / 16) * 512;   // 32768
    if (tid < T1) packB_one(W1, Bp1, 128, tid);
    int tid2 = tid + 25088;
    if (tid2 < T1) packB_one(W1, Bp1, 128, tid2);
}

// ---------------- scatter edges into CSR, payload = src only --------------
__global__ void k_scatter(const int* __restrict__ src, const int* __restrict__ dst,
                          const int* __restrict__ rowPtr, int* __restrict__ cursor,
                          int* __restrict__ esrc, int E) {
    int e = blockIdx.x * blockDim.x + threadIdx.x;
    if (e >= E) return;
    int d = dst[e];
    int pos = rowPtr[d] + atomicAdd(&cursor[d], 1);
    esrc[pos] = src[e];
}

// ------- GEMM with packed B: one wave per 16-row strip, full N ------------
// MFMA 16x16x32 (HW-verified): A[m=lane&15][k=quad*8+j], D: col=lane&15,row=quad*4+reg
template <int KSTEPS, int NTILES>
__global__ __launch_bounds__(256) void k_gemm_pf32(
        const float* __restrict__ A, const bf16_t* __restrict__ Bp,
        bf16_t* __restrict__ C, int M) {
    int wave = (blockIdx.x * blockDim.x + threadIdx.x) >> 6;
    if (wave * 16 >= M) return;
    int lane = threadIdx.x & 63;
    int r16 = lane & 15, quad = lane >> 4;
    const int K = KSTEPS * 32, N = NTILES * 16;
    f32x4 acc[NTILES] = {};
    const float* arow = A + (size_t)(wave * 16 + r16) * K + quad * 8;
#pragma unroll
    for (int s = 0; s < KSTEPS; ++s) {
        const float* ap = arow + s * 32;
        bf16x8 a;
#pragma unroll
        for (int j = 0; j < 8; ++j) a[j] = (bf16_t)ap[j];
        const bf16_t* bp = Bp + ((size_t)(s * NTILES) * 64 + lane) * 8;
#pragma unroll
        for (int t = 0; t < NTILES; ++t) {
            bf16x8 b = *(const bf16x8*)(bp + t * 512);
            acc[t] = __builtin_amdgcn_mfma_f32_16x16x32_bf16(a, b, acc[t], 0, 0, 0);
        }
    }
#pragma unroll
    for (int t = 0; t < NTILES; ++t)
#pragma unroll
        for (int r = 0; r < 4; ++r)
            C[(size_t)(wave * 16 + quad * 4 + r) * N + t * 16 + r16] = (bf16_t)acc[t][r];
}

// ------- layer-1 aggregate + H + (H @ W2) fused ---------------------------
// 16 lanes x bf16x8 (full 128-feat row), 4 parity streams, 2-unroll.
// Loop accumulates A_f = sum_e dinv[src]*XW1[src][f]   (no cross-lane in loop)
// Epilogue (convergent): H_f = relu(d*(A_f + d*x_self) + b1); P = H @ W2 via
// per-lane 8x8 partials reduced with shfl_xor(1,2,4,8); XW2 row written bf16.
__global__ __launch_bounds__(256) void k_agg1(
        const int* __restrict__ rowPtr, const int* __restrict__ esrc,
        const bf16_t* __restrict__ XW1, const float* __restrict__ dinv,
        const float* __restrict__ b1, const float* __restrict__ W2,
        bf16_t* __restrict__ XW2, int n) {
    int wave = (blockIdx.x * blockDim.x + threadIdx.x) >> 6;
    if (wave >= n) return;
    int lane = threadIdx.x & 63;
    int fl = (lane & 15) << 3;   // 8 features of the 128-row
    int h  = lane >> 4;          // parity stream 0..3
    int r0 = rowPtr[wave], r1 = rowPtr[wave + 1];
    float a0[8] = {}, a1[8] = {};
    int k = r0 + h;
    for (; k + 4 < r1; k += 8) {          // 2 independent gathers in flight
        int s0 = esrc[k], s1 = esrc[k + 4];
        float w0 = dinv[s0], w1 = dinv[s1];
        bf16x8 x0 = *(const bf16x8*)(XW1 + ((size_t)s0 << 7) + fl);
        bf16x8 x1 = *(const bf16x8*)(XW1 + ((size_t)s1 << 7) + fl);
#pragma unroll
        for (int j = 0; j < 8; ++j) { a0[j] += (float)x0[j] * w0; a1[j] += (float)x1[j] * w1; }
    }
    if (k < r1) {
        int s0 = esrc[k];
        float w0 = dinv[s0];
        bf16x8 x0 = *(const bf16x8*)(XW1 + ((size_t)s0 << 7) + fl);
#pragma unroll
        for (int j = 0; j < 8; ++j) a0[j] += (float)x0[j] * w0;
    }
#pragma unroll
    for (int j = 0; j < 8; ++j) {        // convergent reduction over 4 streams
        a0[j] += a1[j];
        a0[j] += __shfl_xor(a0[j], 16);
        a0[j] += __shfl_xor(a0[j], 32);
    }
    // ---- epilogue in all 64 lanes (4x redundant across h, broadcast loads)
    float d = dinv[wave];
    bf16x8 xs = *(const bf16x8*)(XW1 + ((size_t)wave << 7) + fl);
    float hrow[8];
#pragma unroll
    for (int j = 0; j < 8; ++j) {
        float v = (a0[j] + (float)xs[j] * d) * d + b1[fl + j];
        hrow[j] = fmaxf(v, 0.f);
    }
    // ---- P = H @ W2 : lane covers feats fl..fl+7 x classes h*8..h*8+7 ----
    float pc[8] = {};
#pragma unroll
    for (int j = 0; j < 8; ++j) {
        f32x8 wr = *(const f32x8*)(W2 + (size_t)(fl + j) * 32 + h * 8);
#pragma unroll
        for (int c = 0; c < 8; ++c) pc[c] += hrow[j] * wr[c];
    }
#pragma unroll
    for (int c = 0; c < 8; ++c) {        // convergent: sum the 16 feat-groups
        pc[c] += __shfl_xor(pc[c], 1);
        pc[c] += __shfl_xor(pc[c], 2);
        pc[c] += __shfl_xor(pc[c], 4);
        pc[c] += __shfl_xor(pc[c], 8);
    }
    if ((lane & 15) == 0) {              // 4 lanes write 16 B each = 64 B/node
        bf16x8 pv;
#pragma unroll
        for (int c = 0; c < 8; ++c) pv[c] = (bf16_t)pc[c];
        *(bf16x8*)(XW2 + ((size_t)wave << 5) + h * 8) = pv;
    }
}

// ------- layer-2 aggregate + log_softmax: 1 class/lane, 2 streams, 2-unroll
__global__ __launch_bounds__(256) void k_agg2(
        const int* __restrict__ rowPtr, const int* __restrict__ esrc,
        const bf16_t* __restrict__ XW2, const float* __restrict__ dinv,
        const float* __restrict__ b2, float* __restrict__ out, int n) {
    int wave = (blockIdx.x * blockDim.x + threadIdx.x) >> 6;
    if (wave >= n) return;
    int lane = threadIdx.x & 63;
    int f = lane & 31, h = lane >> 5;
    int r0 = rowPtr[wave], r1 = rowPtr[wave + 1];
    float acc0 = 0.f, acc1 = 0.f;
    int k = r0 + h;
    for (; k + 2 < r1; k += 4) {
        int s0 = esrc[k], s1 = esrc[k + 2];
        acc0 += (float)XW2[((size_t)s0 << 5) + f] * dinv[s0];
        acc1 += (float)XW2[((size_t)s1 << 5) + f] * dinv[s1];
    }
    if (k < r1) {
        int s0 = esrc[k];
        acc0 += (float)XW2[((size_t)s0 << 5) + f] * dinv[s0];
    }
    float acc = acc0 + acc1;
    acc += __shfl_xor(acc, 32);          // convergent: combine the 2 streams
    float d = dinv[wave];
    float v = (acc + (float)XW2[((size_t)wave << 5) + f] * d) * d + b2[f];
    float mx = v;
#pragma unroll
    for (int m = 16; m >= 1; m >>= 1) mx = fmaxf(mx, __shfl_xor(mx, m));
    float s = expf(v - mx);
#pragma unroll
    for (int m = 16; m >= 1; m >>= 1) s += __shfl_xor(s, m);
    if (lane < 32) out[((size_t)wave << 5) + f] = v - mx - logf(s);
}

extern "C" void kernel_launch(void* const* d_in, const int* in_sizes, int n_in,
                              void* d_out, int out_size, void* d_ws, size_t ws_size,
                              hipStream_t stream) {
    const float* feat = (const float*)d_in[0];
    const int*   eidx = (const int*)d_in[1];
    const float* W1   = (const float*)d_in[2];
    const float* b1   = (const float*)d_in[3];
    const float* W2   = (const float*)d_in[4];
    const float* b2   = (const float*)d_in[5];
    float* out = (float*)d_out;

    const int FIN = 256, HID = 128, NCLS = 32;
    const int N = in_sizes[0] / FIN;   // 100000
    const int E = in_sizes[1] / 2;     // 800000
    const int* src = eidx;
    const int* dst = eidx + E;

    // workspace carve-up (256B aligned)
    char* ws = (char*)d_ws;
    size_t o = 0;
    auto alloc = [&](size_t bytes) -> void* {
        void* p = ws + o;
        o = (o + bytes + 255) & ~(size_t)255;
        return p;
    };
    int*    deg    = (int*)   alloc((size_t)N * 4);   // deg+cursor adjacent:
    int*    cursor = (int*)   alloc((size_t)N * 4);   // single memset below
    size_t  zlen   = (size_t)((char*)(cursor + N) - (char*)deg);
    float*  dinv   = (float*) alloc((size_t)N * 4);
    int*    rowPtr = (int*)   alloc((size_t)(N + 1) * 4);
    int*    bsum   = (int*)   alloc(256 * 4);
    bf16_t* Bp1    = (bf16_t*)alloc((size_t)(FIN / 32) * (HID / 16) * 512 * 2); // 64 KB
    int*    esrc   = (int*)   alloc((size_t)E * 4);        // 3.2 MB
    bf16_t* XW1    = (bf16_t*)alloc((size_t)N * HID * 2);  // 25.6 MB
    bf16_t* XW2    = (bf16_t*)alloc((size_t)N * NCLS * 2); // 6.4 MB

    const int T = 256;
    const int NB = (N + 1023) >> 10;   // 98 scan blocks (<=256)
    hipMemsetAsync(deg, 0, zlen, stream);
    k_deg_count <<<(E + T - 1) / T, T, 0, stream>>>(dst, deg, E);
    k_dinv_scan1<<<NB, T, 0, stream>>>(deg, dinv, bsum, N);
    k_scan2     <<<1, T, 0, stream>>>(bsum, NB, rowPtr, N);
    k_scan3     <<<NB, T, 0, stream>>>(deg, bsum, rowPtr, N, W1, Bp1);
    k_scatter   <<<(E + T - 1) / T, T, 0, stream>>>(src, dst, rowPtr, cursor, esrc, E);

    // layer 1: XW1 = bf16(feat @ W1)   (wave = 16 rows x 128 cols)
    {
        int waves = (N + 15) / 16;
        k_gemm_pf32<8, 8><<<(waves * 64 + T - 1) / T, T, 0, stream>>>(feat, Bp1, XW1, N);
    }
    // agg1 + relu + (H @ W2) fused -> XW2 (bf16)
    k_agg1<<<(N * 64 + T - 1) / T, T, 0, stream>>>(rowPtr, esrc, XW1, dinv, b1, W2, XW2, N);
    // agg2 + log_softmax -> out
    k_agg2<<<(N * 64 + T - 1) / T, T, 0, stream>>>(rowPtr, esrc, XW2, dinv, b2, out, N);
}